// Round 1
// baseline (7548.689 us; speedup 1.0000x reference)
//
#include <hip/hip_runtime.h>
#include <hip/hip_bf16.h>

#define R_TOT 8192
#define NX 32
#define NM 64
#define STRD 33
#define WARM 64

template<typename T> __device__ inline T toST(float v);
template<> __device__ inline float toST<float>(float v) { return v; }
template<> __device__ inline __hip_bfloat16 toST<__hip_bfloat16>(float v) { return __float2bfloat16(v); }
__device__ inline float fromST(float v) { return v; }
__device__ inline float fromST(__hip_bfloat16 v) { return __bfloat162float(v); }

// ---------------- forward: chunked Riccati scan with warm-up halo ----------------
// one wave (64 threads) per chunk; all 32x32 state in LDS.
template<typename ST>
__global__ __launch_bounds__(64) void fwd_kernel(
    const float* __restrict__ hessAll, const float* __restrict__ gradAll,
    const float* __restrict__ A, const float* __restrict__ P,
    const float* __restrict__ initP,
    ST* __restrict__ offOut, ST* __restrict__ xOut, float* __restrict__ uOut,
    int chunkLen)
{
  __shared__ float ap[NX*STRD], apat[NX*STRD], Ps[NX*STRD];
  __shared__ float pred[NX*STRD], sm[NX*STRD], xi[NX*STRD], off[NX*STRD];
  __shared__ float uv[NX], tv[NX];
  const int t = threadIdx.x;
  const int c = blockIdx.x;
  const int r0 = c * chunkLen, r1 = r0 + chunkLen;

  // stage A and P (A temporarily in sm)
  for (int e = t; e < NX*NX; e += 64) {
    int i = e >> 5, j = e & 31;
    Ps[i*STRD+j] = P[e];
    sm[i*STRD+j] = A[e];
  }
  __syncthreads();
  // ap = A @ P
  for (int e = t; e < NX*NX; e += 64) {
    int i = e >> 5, j = e & 31;
    float s = 0.f;
    for (int k = 0; k < NX; ++k) s += sm[i*STRD+k] * Ps[k*STRD+j];
    ap[i*STRD+j] = s;
  }
  __syncthreads();
  // apat = ap @ A^T
  for (int e = t; e < NX*NX; e += 64) {
    int i = e >> 5, j = e & 31;
    float s = 0.f;
    for (int k = 0; k < NX; ++k) s += ap[i*STRD+k] * sm[j*STRD+k];
    apat[i*STRD+j] = s;
  }
  __syncthreads();

  int rstart = r0 - WARM;
  if (rstart < 0) rstart = 0;
  const bool exact = (rstart == 0);   // warm-up reaches r=0: exact initial condition

  for (int e = t; e < NX*NX; e += 64) {
    int i = e >> 5, j = e & 31;
    pred[i*STRD+j] = exact ? initP[e] : Ps[i*STRD+j];  // any SPD guess works (contraction)
    off[i*STRD+j] = 0.f;
    xi[i*STRD+j]  = 0.f;   // upper triangle of xi stays 0 forever
  }
  if (t < NX) uv[t] = 0.f;
  __syncthreads();

  for (int r = rstart; r < r1; ++r) {
    const float m = (r == R_TOT-1) ? 0.f : 1.f;
    const float* hess = hessAll + (size_t)r * (NX*NX);
    // S = pred + hess + m*apat   (factor in place in sm)
    for (int e = t; e < NX*NX; e += 64) {
      int i = e >> 5, j = e & 31;
      sm[i*STRD+j] = pred[i*STRD+j] + hess[e] + m * apat[i*STRD+j];
    }
    __syncthreads();
    // Cholesky (lower, right-looking)
    for (int j = 0; j < NX; ++j) {
      float d = sm[j*STRD+j];
      float inv = rsqrtf(d);
      if (t >= j && t < NX) sm[t*STRD+j] *= inv;   // sm[j][j] -> sqrt(d)
      __syncthreads();
      int kk = j + 1 + (t & 31);
      for (int ib = j + 1; ib < NX; ib += 2) {
        int ii = ib + (t >> 5);
        if (ii < NX && kk <= ii)
          sm[ii*STRD+kk] -= sm[ii*STRD+j] * sm[kk*STRD+j];
      }
      __syncthreads();
    }
    // xi = chol^{-1} (lower); one column per lane
    if (t < NX) {
      const int j = t;
      for (int i = j; i < NX; ++i) {
        float s = (i == j) ? 1.f : 0.f;
        for (int k = j; k < i; ++k) s -= sm[i*STRD+k] * xi[k*STRD+j];
        xi[i*STRD+j] = s / sm[i*STRD+i];
      }
    }
    __syncthreads();
    // u update: tv = grad - u_prev @ off_prev^T ; u_new = tv @ xi^T
    const float* grad = gradAll + (size_t)r * NX;
    if (t < NX) {
      float s = grad[t];
      for (int mI = 0; mI < NX; ++mI) s -= uv[mI] * off[t*STRD+mI];
      tv[t] = s;
    }
    __syncthreads();
    float unew = 0.f;
    if (t < NX) {
      float s = 0.f;
      for (int k = 0; k <= t; ++k) s += tv[k] * xi[t*STRD+k];
      unew = s;
    }
    __syncthreads();
    if (t < NX) uv[t] = unew;
    __syncthreads();
    // off_new = -(xi @ ap)^T : off[j][i] = -sum_{k<=i} xi[i][k] ap[k][j]
    for (int e = t; e < NX*NX; e += 64) {
      int jj = e >> 5, ii = e & 31;
      float s = 0.f;
      for (int k = 0; k <= ii; ++k) s += xi[ii*STRD+k] * ap[k*STRD+jj];
      off[jj*STRD+ii] = -s;
    }
    __syncthreads();
    // pred = P - off off^T
    for (int e = t; e < NX*NX; e += 64) {
      int i = e >> 5, j = e & 31;
      float s = Ps[i*STRD+j];
      for (int k = 0; k < NX; ++k) s -= off[i*STRD+k] * off[j*STRD+k];
      pred[i*STRD+j] = s;
    }
    // store results for real rows
    if (r >= r0) {
      size_t base = (size_t)r * (NX*NX);
      for (int e = t; e < NX*NX; e += 64) {
        int i = e >> 5, j = e & 31;
        offOut[base + e] = toST<ST>(off[i*STRD+j]);
        xOut[base + e]   = toST<ST>(xi[i*STRD+j]);
      }
      if (t < NX) uOut[(size_t)r*NX + t] = unew;
    }
    __syncthreads();
  }
}

// ---------------- backward: chunked reverse linear scan with warm-up halo ----------------
// 256 threads per chunk. vw_r = (g_r - vw_{r+1} @ off_r) @ xi_r ; out_r = vw[1:] + vw[0]
template<typename ST>
__global__ __launch_bounds__(256) void bwd_kernel(
    const ST* __restrict__ offIn, const ST* __restrict__ xIn, const float* __restrict__ uIn,
    const float* __restrict__ epsx, float* __restrict__ outp, int chunkLen)
{
  __shared__ float vw[(NM+1)*STRD], bb[(NM+1)*STRD], off[NX*STRD], xi[NX*STRD];
  const int t = threadIdx.x;
  const int c = blockIdx.x;
  const int r0 = c * chunkLen, r1 = r0 + chunkLen;
  int rstart = r1 + WARM; if (rstart > R_TOT) rstart = R_TOT;  // vw=0 exact at r=R

  for (int e = t; e < (NM+1)*NX; e += 256) { int i = e >> 5, j = e & 31; vw[i*STRD+j] = 0.f; }
  __syncthreads();

  for (int r = rstart - 1; r >= r0; --r) {
    size_t base = (size_t)r * (NX*NX);
    for (int e = t; e < NX*NX; e += 256) {
      int i = e >> 5, j = e & 31;
      off[i*STRD+j] = fromST(offIn[base+e]);
      xi[i*STRD+j]  = fromST(xIn[base+e]);
    }
    __syncthreads();
    const float* eps_r = epsx + (size_t)r * (NM*NX);
    const float* u_r   = uIn + (size_t)r * NX;
    // bb = g - vw @ off
    for (int e = t; e < (NM+1)*NX; e += 256) {
      int i = e >> 5, j = e & 31;
      float s = (i == 0) ? u_r[j] : eps_r[(i-1)*NX + j];
      for (int k = 0; k < NX; ++k) s -= vw[i*STRD+k] * off[k*STRD+j];
      bb[i*STRD+j] = s;
    }
    __syncthreads();
    // vw = bb @ xi   (xi lower-triangular: k >= j)
    for (int e = t; e < (NM+1)*NX; e += 256) {
      int i = e >> 5, j = e & 31;
      float s = 0.f;
      for (int k = j; k < NX; ++k) s += bb[i*STRD+k] * xi[k*STRD+j];
      vw[i*STRD+j] = s;
    }
    __syncthreads();
    if (r < r1) {
      float* out_r = outp + (size_t)r * (NM*NX);
      for (int e = t; e < NM*NX; e += 256) {
        int i = e >> 5, j = e & 31;
        out_r[e] = vw[(i+1)*STRD+j] + vw[j];
      }
    }
    __syncthreads();
  }
}

extern "C" void kernel_launch(void* const* d_in, const int* in_sizes, int n_in,
                              void* d_out, int out_size, void* d_ws, size_t ws_size,
                              hipStream_t stream) {
  const float* hess  = (const float*)d_in[0];
  const float* grads = (const float*)d_in[1];
  const float* A     = (const float*)d_in[2];
  const float* P     = (const float*)d_in[3];
  const float* initP = (const float*)d_in[4];
  const float* epsx  = (const float*)d_in[5];
  float* outp = (float*)d_out;

  const int CF = 512, LF = R_TOT / CF;
  const int CB = 512, LB = R_TOT / CB;

  const size_t mats = (size_t)R_TOT * NX * NX;
  const size_t needF32 = 2ull * mats * sizeof(float) + (size_t)R_TOT * NX * sizeof(float);

  if (ws_size >= needF32) {
    float* offS = (float*)d_ws;
    float* xS   = offS + mats;
    float* uS   = xS + mats;
    fwd_kernel<float><<<dim3(CF), dim3(64), 0, stream>>>(hess, grads, A, P, initP, offS, xS, uS, LF);
    bwd_kernel<float><<<dim3(CB), dim3(256), 0, stream>>>(offS, xS, uS, epsx, outp, LB);
  } else {
    __hip_bfloat16* offS = (__hip_bfloat16*)d_ws;
    __hip_bfloat16* xS   = offS + mats;
    float* uS            = (float*)(xS + mats);
    fwd_kernel<__hip_bfloat16><<<dim3(CF), dim3(64), 0, stream>>>(hess, grads, A, P, initP, offS, xS, uS, LF);
    bwd_kernel<__hip_bfloat16><<<dim3(CB), dim3(256), 0, stream>>>(offS, xS, uS, epsx, outp, LB);
  }
}

// Round 2
// 2576.766 us; speedup vs baseline: 2.9295x; 2.9295x over previous
//
#include <hip/hip_runtime.h>
#include <hip/hip_bf16.h>

#define R_TOT 8192
#define NX 32
#define NM 64
#define STRD 33
#define WARM 24
#define CHUNK 8
#define NCH (R_TOT / CHUNK)

template<typename T> __device__ inline T toST(float v);
template<> __device__ inline float toST<float>(float v) { return v; }
template<> __device__ inline __hip_bfloat16 toST<__hip_bfloat16>(float v) { return __float2bfloat16(v); }
__device__ inline float fromST(float v) { return v; }
__device__ inline float fromST(__hip_bfloat16 v) { return __bfloat162float(v); }

// single-wave "barrier": lockstep wave64 + drain LDS ops. Valid only for 64-thread blocks.
__device__ inline void wsync() { asm volatile("s_waitcnt lgkmcnt(0)" ::: "memory"); }

// ---------------- forward: chunked Riccati scan with warm-up halo ----------------
// one wave (64 threads) per chunk; LDL^T factorization, register-column inversion.
template<typename ST>
__global__ __launch_bounds__(64) void fwd_kernel(
    const float* __restrict__ hessAll, const float* __restrict__ gradAll,
    const float* __restrict__ A, const float* __restrict__ P,
    const float* __restrict__ initP,
    ST* __restrict__ offOut, ST* __restrict__ xOut, float* __restrict__ uOut,
    int chunkLen)
{
  __shared__ float ap[NX*STRD], apat[NX*STRD], Ps[NX*STRD];
  __shared__ float pred[NX*STRD], sm[NX*STRD], xi[NX*STRD], off[NX*STRD];
  __shared__ float uv[NX], tv[NX], dinv[NX], sqd[NX];
  const int t = threadIdx.x;
  const int c = blockIdx.x;
  const int r0 = c * chunkLen, r1 = r0 + chunkLen;

  // stage A and P (A temporarily in sm)
  for (int e = t; e < NX*NX; e += 64) {
    int i = e >> 5, j = e & 31;
    Ps[i*STRD+j] = P[e];
    sm[i*STRD+j] = A[e];
  }
  wsync();
  // ap = A @ P
  for (int e = t; e < NX*NX; e += 64) {
    int i = e >> 5, j = e & 31;
    float s = 0.f;
    for (int k = 0; k < NX; ++k) s += sm[i*STRD+k] * Ps[k*STRD+j];
    ap[i*STRD+j] = s;
  }
  wsync();
  // apat = ap @ A^T
  for (int e = t; e < NX*NX; e += 64) {
    int i = e >> 5, j = e & 31;
    float s = 0.f;
    for (int k = 0; k < NX; ++k) s += ap[i*STRD+k] * sm[j*STRD+k];
    apat[i*STRD+j] = s;
  }
  wsync();

  int rstart = r0 - WARM;
  if (rstart < 0) rstart = 0;
  const bool exact = (rstart == 0);   // warm-up reaches r=0: exact initial condition

  for (int e = t; e < NX*NX; e += 64) {
    int i = e >> 5, j = e & 31;
    pred[i*STRD+j] = exact ? initP[e] : Ps[i*STRD+j];  // any SPD guess works (contraction)
    off[i*STRD+j] = 0.f;
    xi[i*STRD+j]  = 0.f;
  }
  if (t < NX) uv[t] = 0.f;
  wsync();

  for (int r = rstart; r < r1; ++r) {
    const bool last = (r == R_TOT-1);
    const float* hess = hessAll + (size_t)r * (NX*NX);
    const float4* h4 = (const float4*)hess;
    // S = pred + hess + m*apat   (raw matrix into sm), vectorized hess loads
    for (int e = t; e < (NX*NX)/4; e += 64) {
      int i = e >> 3, j0 = (e & 7) * 4;
      float4 hv = h4[e];
      float v0 = pred[i*STRD+j0+0] + hv.x;
      float v1 = pred[i*STRD+j0+1] + hv.y;
      float v2 = pred[i*STRD+j0+2] + hv.z;
      float v3 = pred[i*STRD+j0+3] + hv.w;
      if (!last) {
        v0 += apat[i*STRD+j0+0]; v1 += apat[i*STRD+j0+1];
        v2 += apat[i*STRD+j0+2]; v3 += apat[i*STRD+j0+3];
      }
      sm[i*STRD+j0+0] = v0; sm[i*STRD+j0+1] = v1;
      sm[i*STRD+j0+2] = v2; sm[i*STRD+j0+3] = v3;
    }
    wsync();
    // LDL^T, right-looking, columns kept unscaled: sm[i][j] = l~_ij * d_j, diag = d_j.
    // one wsync per column.
    for (int j = 0; j < NX-1; ++j) {
      float invd = 1.0f / sm[j*STRD+j];     // broadcast read
      int kk = j + 1 + (t & 31);
      for (int ib = j + 1; ib < NX; ib += 2) {
        int ii = ib + (t >> 5);
        if (ii < NX && kk <= ii)
          sm[ii*STRD+kk] -= sm[ii*STRD+j] * (sm[kk*STRD+j] * invd);
      }
      wsync();
    }
    if (t < NX) { float d = sm[t*STRD+t]; dinv[t] = 1.0f / d; sqd[t] = sqrtf(d); }
    wsync();
    // zeta = D^{-1} L~^{-1}, lane t holds column t in registers (t>=32 inert, computes zeros)
    // recursion: zeta[i][j] = -dinv_i * sum_{k<i} sm[i][k]*zeta[k][j], zeta[j][j]=dinv_j
    // (zc[k]=0 for k<j makes the sum start at k=j automatically)
    {
      float zc[NX];
      const int j = t;
      #pragma unroll
      for (int i = 0; i < NX; ++i) {
        float s = 0.f;
        #pragma unroll
        for (int k = 0; k < i; ++k) s += sm[i*STRD+k] * zc[k];   // broadcast reads
        float di = dinv[i];
        float v = -di * s;
        if (i == j) v = di;
        zc[i] = v;
      }
      if (t < NX) {
        #pragma unroll
        for (int i = 0; i < NX; ++i) xi[i*STRD+t] = zc[i] * sqd[i];  // xi = chol^{-1}
      }
    }
    wsync();
    // u update: tv = grad - u_prev @ off_prev^T ; u_new = tv @ xi^T
    const float* grad = gradAll + (size_t)r * NX;
    if (t < NX) {
      float s = grad[t];
      for (int mI = 0; mI < NX; ++mI) s -= uv[mI] * off[t*STRD+mI];
      tv[t] = s;
    }
    wsync();
    float unew = 0.f;
    if (t < NX) {
      float s = 0.f;
      for (int k = 0; k <= t; ++k) s += tv[k] * xi[t*STRD+k];
      unew = s;
    }
    wsync();
    if (t < NX) uv[t] = unew;
    wsync();
    // off_new = -(xi @ ap)^T : off[j][i] = -sum_{k<=i} xi[i][k] ap[k][j]
    for (int e = t; e < NX*NX; e += 64) {
      int jj = e >> 5, ii = e & 31;
      float s = 0.f;
      for (int k = 0; k <= ii; ++k) s += xi[ii*STRD+k] * ap[k*STRD+jj];
      off[jj*STRD+ii] = -s;
    }
    wsync();
    // pred = P - off off^T
    for (int e = t; e < NX*NX; e += 64) {
      int i = e >> 5, j = e & 31;
      float s = Ps[i*STRD+j];
      for (int k = 0; k < NX; ++k) s -= off[i*STRD+k] * off[j*STRD+k];
      pred[i*STRD+j] = s;
    }
    // store results for real rows
    if (r >= r0) {
      size_t base = (size_t)r * (NX*NX);
      for (int e = t; e < NX*NX; e += 64) {
        int i = e >> 5, j = e & 31;
        offOut[base + e] = toST<ST>(off[i*STRD+j]);
        xOut[base + e]   = toST<ST>(xi[i*STRD+j]);
      }
      if (t < NX) uOut[(size_t)r*NX + t] = unew;
    }
    wsync();
  }
}

// ---------------- backward: chunked reverse linear scan with warm-up halo ----------------
// 256 threads per chunk. vw_r = (g_r - vw_{r+1} @ off_r) @ xi_r ; out_r = vw[1:] + vw[0]
template<typename ST>
__global__ __launch_bounds__(256) void bwd_kernel(
    const ST* __restrict__ offIn, const ST* __restrict__ xIn, const float* __restrict__ uIn,
    const float* __restrict__ epsx, float* __restrict__ outp, int chunkLen)
{
  __shared__ float vw[(NM+1)*STRD], bb[(NM+1)*STRD], off[NX*STRD], xi[NX*STRD];
  const int t = threadIdx.x;
  const int c = blockIdx.x;
  const int r0 = c * chunkLen, r1 = r0 + chunkLen;
  int rstart = r1 + WARM; if (rstart > R_TOT) rstart = R_TOT;  // vw=0 exact at r=R

  for (int e = t; e < (NM+1)*NX; e += 256) { int i = e >> 5, j = e & 31; vw[i*STRD+j] = 0.f; }
  __syncthreads();

  for (int r = rstart - 1; r >= r0; --r) {
    size_t base = (size_t)r * (NX*NX);
    for (int e = t; e < NX*NX; e += 256) {
      int i = e >> 5, j = e & 31;
      off[i*STRD+j] = fromST(offIn[base+e]);
      xi[i*STRD+j]  = fromST(xIn[base+e]);
    }
    __syncthreads();
    const float* eps_r = epsx + (size_t)r * (NM*NX);
    const float* u_r   = uIn + (size_t)r * NX;
    // bb = g - vw @ off
    for (int e = t; e < (NM+1)*NX; e += 256) {
      int i = e >> 5, j = e & 31;
      float s = (i == 0) ? u_r[j] : eps_r[(i-1)*NX + j];
      for (int k = 0; k < NX; ++k) s -= vw[i*STRD+k] * off[k*STRD+j];
      bb[i*STRD+j] = s;
    }
    __syncthreads();
    // vw = bb @ xi   (xi lower-triangular: k >= j)
    for (int e = t; e < (NM+1)*NX; e += 256) {
      int i = e >> 5, j = e & 31;
      float s = 0.f;
      for (int k = j; k < NX; ++k) s += bb[i*STRD+k] * xi[k*STRD+j];
      vw[i*STRD+j] = s;
    }
    __syncthreads();
    if (r < r1) {
      float* out_r = outp + (size_t)r * (NM*NX);
      for (int e = t; e < NM*NX; e += 256) {
        int i = e >> 5, j = e & 31;
        out_r[e] = vw[(i+1)*STRD+j] + vw[j];
      }
    }
    __syncthreads();
  }
}

extern "C" void kernel_launch(void* const* d_in, const int* in_sizes, int n_in,
                              void* d_out, int out_size, void* d_ws, size_t ws_size,
                              hipStream_t stream) {
  const float* hess  = (const float*)d_in[0];
  const float* grads = (const float*)d_in[1];
  const float* A     = (const float*)d_in[2];
  const float* P     = (const float*)d_in[3];
  const float* initP = (const float*)d_in[4];
  const float* epsx  = (const float*)d_in[5];
  float* outp = (float*)d_out;

  const int CF = NCH, LF = CHUNK;
  const int CB = NCH, LB = CHUNK;

  const size_t mats = (size_t)R_TOT * NX * NX;
  const size_t needF32 = 2ull * mats * sizeof(float) + (size_t)R_TOT * NX * sizeof(float);

  if (ws_size >= needF32) {
    float* offS = (float*)d_ws;
    float* xS   = offS + mats;
    float* uS   = xS + mats;
    fwd_kernel<float><<<dim3(CF), dim3(64), 0, stream>>>(hess, grads, A, P, initP, offS, xS, uS, LF);
    bwd_kernel<float><<<dim3(CB), dim3(256), 0, stream>>>(offS, xS, uS, epsx, outp, LB);
  } else {
    __hip_bfloat16* offS = (__hip_bfloat16*)d_ws;
    __hip_bfloat16* xS   = offS + mats;
    float* uS            = (float*)(xS + mats);
    fwd_kernel<__hip_bfloat16><<<dim3(CF), dim3(64), 0, stream>>>(hess, grads, A, P, initP, offS, xS, uS, LF);
    bwd_kernel<__hip_bfloat16><<<dim3(CB), dim3(256), 0, stream>>>(offS, xS, uS, epsx, outp, LB);
  }
}

// Round 3
// 1265.576 us; speedup vs baseline: 5.9646x; 2.0360x over previous
//
#include <hip/hip_runtime.h>
#include <hip/hip_bf16.h>

#define R_TOT 8192
#define NX 32
#define NM 64
#define STRD 33
#define WARM 16
#define CHUNKF 4
#define CHUNKB 8

template<typename T> __device__ inline T toST(float v);
template<> __device__ inline float toST<float>(float v) { return v; }
template<> __device__ inline __hip_bfloat16 toST<__hip_bfloat16>(float v) { return __float2bfloat16(v); }
__device__ inline float fromST(float v) { return v; }
__device__ inline float fromST(__hip_bfloat16 v) { return __bfloat162float(v); }

// single-wave "barrier": lockstep wave64 + drain LDS ops. Valid only for 64-thread blocks.
__device__ inline void wsync() { asm volatile("s_waitcnt lgkmcnt(0)" ::: "memory"); }

// ---------------- precompute ap = A@P, apat = ap@A^T (shared by all chunks) --------------
__global__ __launch_bounds__(64) void precomp_kernel(
    const float* __restrict__ A, const float* __restrict__ P,
    float* __restrict__ apG, float* __restrict__ apatG)
{
  __shared__ float As[NX*STRD], Ps[NX*STRD], aps[NX*STRD];
  const int t = threadIdx.x;
  for (int e = t; e < NX*NX; e += 64) {
    int i = e >> 5, j = e & 31;
    As[i*STRD+j] = A[e];
    Ps[i*STRD+j] = P[e];
  }
  wsync();
  for (int e = t; e < NX*NX; e += 64) {
    int i = e >> 5, j = e & 31;
    float s = 0.f;
    for (int k = 0; k < NX; ++k) s += As[i*STRD+k] * Ps[k*STRD+j];
    aps[i*STRD+j] = s;
    apG[e] = s;
  }
  wsync();
  for (int e = t; e < NX*NX; e += 64) {
    int i = e >> 5, j = e & 31;
    float s = 0.f;
    for (int k = 0; k < NX; ++k) s += aps[i*STRD+k] * As[j*STRD+k];
    apatG[e] = s;
  }
}

// ---------------- forward: chunked Riccati scan, register-heavy ----------------
// one wave per chunk. Lane owns elements (i = (t>>5)+2m, j = t&31), m=0..15.
template<typename ST>
__global__ __launch_bounds__(64, 2) void fwd_kernel(
    const float* __restrict__ hessAll, const float* __restrict__ gradAll,
    const float* __restrict__ apG, const float* __restrict__ apatG,
    const float* __restrict__ P, const float* __restrict__ initP,
    ST* __restrict__ offOut, ST* __restrict__ xOut, float* __restrict__ uOut)
{
  __shared__ float ap[NX*STRD], sm[NX*STRD], xi[NX*STRD], off[NX*STRD];
  __shared__ float uv[NX], tv[NX], dinv[NX], sqd[NX];
  const int t = threadIdx.x;
  const int lane = t & 31, half = t >> 5;
  const int c = blockIdx.x;
  const int r0 = c * CHUNKF, r1 = r0 + CHUNKF;

  float PsR[16], apatR[16], predR[16], hessR[16];
  float gradR;

  #pragma unroll
  for (int m = 0; m < 16; ++m) {
    int e = t + 64*m;
    ap[(half + 2*m)*STRD + lane] = apG[e];
    PsR[m]   = P[e];
    apatR[m] = apatG[e];
  }
  wsync();

  int rstart = r0 - WARM;
  if (rstart < 0) rstart = 0;
  const bool exact = (rstart == 0);

  #pragma unroll
  for (int m = 0; m < 16; ++m) {
    predR[m] = exact ? initP[t + 64*m] : PsR[m];   // any SPD init works (contraction)
    off[(half + 2*m)*STRD + lane] = 0.f;
  }
  if (t < NX) uv[t] = 0.f;
  wsync();

  // preload first step's hess/grad
  {
    const float* hess = hessAll + (size_t)rstart * (NX*NX);
    #pragma unroll
    for (int m = 0; m < 16; ++m) hessR[m] = hess[t + 64*m];
    gradR = gradAll[(size_t)rstart * NX + lane];
  }

  for (int r = rstart; r < r1; ++r) {
    const bool last = (r == R_TOT-1);
    // ---- S = pred + hess (+ apat) into sm ----
    #pragma unroll
    for (int m = 0; m < 16; ++m) {
      float v = predR[m] + hessR[m];
      if (!last) v += apatR[m];
      sm[(half + 2*m)*STRD + lane] = v;
    }
    wsync();
    // prefetch next step's hess (consumed above; latency hidden under chol)
    if (r + 1 < r1) {
      const float* hn = hessAll + (size_t)(r+1) * (NX*NX);
      #pragma unroll
      for (int m = 0; m < 16; ++m) hessR[m] = hn[t + 64*m];
    }
    // ---- LDL^T, right-looking, unscaled columns: sm[i][j] = l~_ij * d_j ----
    for (int j = 0; j < NX-1; ++j) {
      float invd = 1.0f / sm[j*STRD+j];        // broadcast read
      int kk = j + 1 + lane;
      bool act = kk < NX;
      float f = act ? sm[kk*STRD+j] * invd : 0.f;
      for (int ib = j + 1 + half; ib < NX; ib += 2) {
        if (act && kk <= ib)
          sm[ib*STRD+kk] -= sm[ib*STRD+j] * f;
      }
      wsync();
    }
    if (t < NX) { float d = sm[t*STRD+t]; dinv[t] = 1.0f/d; sqd[t] = sqrtf(d); }
    wsync();
    // ---- zeta = D^{-1} L~^{-1}; lane t holds column t; xi = chol^{-1} ----
    {
      float zc[NX];
      #pragma unroll
      for (int i = 0; i < NX; ++i) {
        float s = 0.f;
        #pragma unroll
        for (int k = 0; k < i; ++k) s += sm[i*STRD+k] * zc[k];   // broadcast reads
        float di = dinv[i];
        zc[i] = (i == t) ? di : -di * s;
      }
      if (t < NX) {
        if (r >= r0) {
          size_t base = (size_t)r * (NX*NX);
          #pragma unroll
          for (int i = 0; i < NX; ++i) {
            float v = zc[i] * sqd[i];
            xi[i*STRD + t] = v;
            xOut[base + i*NX + t] = toST<ST>(v);
          }
        } else {
          #pragma unroll
          for (int i = 0; i < NX; ++i) xi[i*STRD + t] = zc[i] * sqd[i];
        }
      }
    }
    wsync();
    // ---- u update: tv = grad - u_prev @ off_prev^T ; u_new = tv @ xi^T ----
    if (t < NX) {
      float s = gradR;
      for (int m = 0; m < NX; ++m) s -= uv[m] * off[t*STRD+m];
      tv[t] = s;
    }
    wsync();
    float unew = 0.f;
    if (t < NX) {
      float s = 0.f;
      for (int k = 0; k < NX; ++k) s += tv[k] * xi[t*STRD+k];
      unew = s;
    }
    wsync();
    if (t < NX) {
      uv[t] = unew;
      if (r >= r0) uOut[(size_t)r*NX + t] = unew;
    }
    if (r + 1 < r1) gradR = gradAll[(size_t)(r+1) * NX + lane];
    wsync();   // uv visible; off reads (u phase) drained before overwrite below
    // ---- off[jj][ii] = -sum_k xi[ii][k] ap[k][jj]; ii = lane, jj = half+2m ----
    {
      float offR[16];
      #pragma unroll
      for (int m = 0; m < 16; ++m) offR[m] = 0.f;
      for (int k = 0; k < NX; ++k) {
        float xv = xi[lane*STRD + k];            // conflict-free
        #pragma unroll
        for (int m = 0; m < 16; ++m)
          offR[m] += xv * ap[k*STRD + half + 2*m];   // broadcast
      }
      if (r >= r0) {
        size_t base = (size_t)r * (NX*NX);
        #pragma unroll
        for (int m = 0; m < 16; ++m) {
          float v = -offR[m];
          off[(half + 2*m)*STRD + lane] = v;
          offOut[base + (half + 2*m)*NX + lane] = toST<ST>(v);
        }
      } else {
        #pragma unroll
        for (int m = 0; m < 16; ++m)
          off[(half + 2*m)*STRD + lane] = -offR[m];
      }
    }
    wsync();
    // ---- pred = P - off @ off^T (into registers) ----
    #pragma unroll
    for (int m = 0; m < 16; ++m) predR[m] = PsR[m];
    for (int k = 0; k < NX; ++k) {
      float fj = off[lane*STRD + k];             // conflict-free
      #pragma unroll
      for (int m = 0; m < 16; ++m)
        predR[m] -= off[(half + 2*m)*STRD + k] * fj;   // broadcast
    }
    wsync();
  }
}

// ---------------- backward: chunked reverse linear scan ----------------
// 256 threads/chunk. Thread owns rows i = grp+8m (grp = t>>5), col j = t&31.
template<typename ST>
__global__ __launch_bounds__(256, 4) void bwd_kernel(
    const ST* __restrict__ offIn, const ST* __restrict__ xIn, const float* __restrict__ uIn,
    const float* __restrict__ epsx, float* __restrict__ outp)
{
  __shared__ float vw[(NM+1)*STRD], bb[(NM+1)*STRD], off[NX*STRD], xi[NX*STRD];
  const int t = threadIdx.x;
  const int lane = t & 31, grp = t >> 5;
  const int c = blockIdx.x;
  const int r0 = c * CHUNKB, r1 = r0 + CHUNKB;
  int rstart = r1 + WARM; if (rstart > R_TOT) rstart = R_TOT;
  const bool has64 = (grp == 0);

  for (int e = t; e < (NM+1)*NX; e += 256) { int i = e >> 5, j = e & 31; vw[i*STRD+j] = 0.f; }

  float offR[4], xiR[4], gR[9];
  {
    int r = rstart - 1;
    size_t base = (size_t)r * (NX*NX);
    #pragma unroll
    for (int m = 0; m < 4; ++m) {
      offR[m] = fromST(offIn[base + t + 256*m]);
      xiR[m]  = fromST(xIn[base + t + 256*m]);
    }
    const float* eps_r = epsx + (size_t)r * (NM*NX);
    const float* u_r   = uIn + (size_t)r * NX;
    #pragma unroll
    for (int m = 0; m < 8; ++m) {
      int i = grp + 8*m;
      gR[m] = (i == 0) ? u_r[lane] : eps_r[(i-1)*NX + lane];
    }
    gR[8] = has64 ? eps_r[63*NX + lane] : 0.f;
  }
  __syncthreads();

  for (int r = rstart - 1; r >= r0; --r) {
    // deposit this step's off/xi; move g into acc
    float acc[9];
    #pragma unroll
    for (int m = 0; m < 9; ++m) acc[m] = gR[m];
    #pragma unroll
    for (int m = 0; m < 4; ++m) {
      off[(grp + 8*m)*STRD + lane] = offR[m];
      xi[(grp + 8*m)*STRD + lane]  = xiR[m];
    }
    __syncthreads();
    // prefetch next (lower) step's inputs
    if (r > r0) {
      size_t base = (size_t)(r-1) * (NX*NX);
      #pragma unroll
      for (int m = 0; m < 4; ++m) {
        offR[m] = fromST(offIn[base + t + 256*m]);
        xiR[m]  = fromST(xIn[base + t + 256*m]);
      }
      const float* eps_n = epsx + (size_t)(r-1) * (NM*NX);
      const float* u_n   = uIn + (size_t)(r-1) * NX;
      #pragma unroll
      for (int m = 0; m < 8; ++m) {
        int i = grp + 8*m;
        gR[m] = (i == 0) ? u_n[lane] : eps_n[(i-1)*NX + lane];
      }
      if (has64) gR[8] = eps_n[63*NX + lane];
    }
    // ---- bb = g - vw @ off ----
    for (int k = 0; k < NX; ++k) {
      float fo = off[k*STRD + lane];             // conflict-free
      #pragma unroll
      for (int m = 0; m < 8; ++m) acc[m] -= vw[(grp + 8*m)*STRD + k] * fo;
      if (has64) acc[8] -= vw[64*STRD + k] * fo;
    }
    #pragma unroll
    for (int m = 0; m < 8; ++m) bb[(grp + 8*m)*STRD + lane] = acc[m];
    if (has64) bb[64*STRD + lane] = acc[8];
    __syncthreads();
    // ---- vw = bb @ xi (xi strictly lower-triangular-from-chol^{-1}: zeros above) ----
    float vacc[9];
    #pragma unroll
    for (int m = 0; m < 9; ++m) vacc[m] = 0.f;
    for (int k = 0; k < NX; ++k) {
      float fx = xi[k*STRD + lane];              // conflict-free
      #pragma unroll
      for (int m = 0; m < 8; ++m) vacc[m] += bb[(grp + 8*m)*STRD + k] * fx;
      if (has64) vacc[8] += bb[64*STRD + k] * fx;
    }
    #pragma unroll
    for (int m = 0; m < 8; ++m) vw[(grp + 8*m)*STRD + lane] = vacc[m];
    if (has64) vw[64*STRD + lane] = vacc[8];
    __syncthreads();
    // ---- out_r[i][j] = vw[i+1][j] + vw[0][j], rows i = grp+8m ----
    if (r < r1) {
      float v0 = vw[lane];
      float* out_r = outp + (size_t)r * (NM*NX);
      #pragma unroll
      for (int m = 0; m < 8; ++m)
        out_r[(grp + 8*m)*NX + lane] = vw[(grp + 8*m + 1)*STRD + lane] + v0;
    }
    __syncthreads();
  }
}

extern "C" void kernel_launch(void* const* d_in, const int* in_sizes, int n_in,
                              void* d_out, int out_size, void* d_ws, size_t ws_size,
                              hipStream_t stream) {
  const float* hess  = (const float*)d_in[0];
  const float* grads = (const float*)d_in[1];
  const float* A     = (const float*)d_in[2];
  const float* P     = (const float*)d_in[3];
  const float* initP = (const float*)d_in[4];
  const float* epsx  = (const float*)d_in[5];
  float* outp = (float*)d_out;

  const size_t mats = (size_t)R_TOT * NX * NX;
  const size_t uN   = (size_t)R_TOT * NX;
  const size_t needF32 = 2ull * mats * sizeof(float) + uN * sizeof(float) + 2048 * sizeof(float);

  if (ws_size >= needF32) {
    float* offS  = (float*)d_ws;
    float* xS    = offS + mats;
    float* uS    = xS + mats;
    float* apG   = uS + uN;
    float* apatG = apG + 1024;
    precomp_kernel<<<dim3(1), dim3(64), 0, stream>>>(A, P, apG, apatG);
    fwd_kernel<float><<<dim3(R_TOT/CHUNKF), dim3(64), 0, stream>>>(
        hess, grads, apG, apatG, P, initP, offS, xS, uS);
    bwd_kernel<float><<<dim3(R_TOT/CHUNKB), dim3(256), 0, stream>>>(
        offS, xS, uS, epsx, outp);
  } else {
    __hip_bfloat16* offS = (__hip_bfloat16*)d_ws;
    __hip_bfloat16* xS   = offS + mats;
    float* uS            = (float*)(xS + mats);
    float* apG           = uS + uN;
    float* apatG         = apG + 1024;
    precomp_kernel<<<dim3(1), dim3(64), 0, stream>>>(A, P, apG, apatG);
    fwd_kernel<__hip_bfloat16><<<dim3(R_TOT/CHUNKF), dim3(64), 0, stream>>>(
        hess, grads, apG, apatG, P, initP, offS, xS, uS);
    bwd_kernel<__hip_bfloat16><<<dim3(R_TOT/CHUNKB), dim3(256), 0, stream>>>(
        offS, xS, uS, epsx, outp);
  }
}